// Round 7
// baseline (100.356 us; speedup 1.0000x reference)
//
#include <hip/hip_runtime.h>
#include <hip/hip_bf16.h>

#define BATCH 8192
#define DMODEL 4096
#define NEXP 64

typedef __attribute__((ext_vector_type(8))) short short8;   // 8 bf16 (4 VGPR)
typedef __attribute__((ext_vector_type(4))) float f32x4;

#define WF_PLANE 262144   // ushorts per plane: 128 ksteps * 4 cfrags * 64 lanes * 8
#define WF_FLOATS 393216  // 3 planes * 262144 ushorts / 2 = floats occupied by WF

// ============================================================================
// Build W planes (h/m/l bf16 split) in MFMA B-fragment order:
// WF[plane][ks][cf][lane][j] <- bf16 split of W[e = cf*16 + (l&15)][k = ks*32 + (l>>4)*8 + j]
// ============================================================================
__global__ __launch_bounds__(256) void build_wf(const float* __restrict__ W,
                                                unsigned short* __restrict__ WF)
{
    const int gid = blockIdx.x * 256 + threadIdx.x;   // 0..32767
    const int ks = gid >> 8;
    const int cf = (gid >> 6) & 3;
    const int l  = gid & 63;
    const int e  = cf * 16 + (l & 15);
    const int k0 = ks * 32 + (l >> 4) * 8;
    const float* src = W + (size_t)e * DMODEL + k0;

    unsigned short hu[8], mu[8], lu[8];
#pragma unroll
    for (int j = 0; j < 8; ++j) {
        const float xv = src[j];
        const __hip_bfloat16 h = __float2bfloat16(xv);
        const float r1 = xv - __bfloat162float(h);
        const __hip_bfloat16 m = __float2bfloat16(r1);
        const float r2 = r1 - __bfloat162float(m);
        const __hip_bfloat16 lo = __float2bfloat16(r2);
        hu[j] = __builtin_bit_cast(unsigned short, h);
        mu[j] = __builtin_bit_cast(unsigned short, m);
        lu[j] = __builtin_bit_cast(unsigned short, lo);
    }
    const size_t off = ((size_t)(ks * 4 + cf) * 64 + l) * 8;
#pragma unroll
    for (int j = 0; j < 8; ++j) {
        WF[off + j] = hu[j];
        WF[WF_PLANE + off + j] = mu[j];
        WF[2 * WF_PLANE + off + j] = lu[j];
    }
}

// ============================================================================
// MFMA GEMM: 1 wave per block, 32 rows x 64 experts, no LDS, no barriers.
// 6-product bf16 split (hH,hM,mH,hL,lH,mM) == fp32-accurate logits.
// Register-dieted: A single-buffer prefetch, B rolled in 2-cf groups,
// product-major MFMA order (4 independent acc chains).
// Grid = 256 row-groups x S k-splits.  part[s][row][e].
// ============================================================================

#define CVT1(V, J, AH, AM, AL) {                                              \
    const float xv_ = (V);                                                    \
    const __hip_bfloat16 h_ = __float2bfloat16(xv_);                          \
    const float r1_ = xv_ - __bfloat162float(h_);                             \
    const __hip_bfloat16 m_ = __float2bfloat16(r1_);                          \
    const float r2_ = r1_ - __bfloat162float(m_);                             \
    const __hip_bfloat16 l_ = __float2bfloat16(r2_);                          \
    AH[J] = (short)__builtin_bit_cast(unsigned short, h_);                    \
    AM[J] = (short)__builtin_bit_cast(unsigned short, m_);                    \
    AL[J] = (short)__builtin_bit_cast(unsigned short, l_); }

#define CVT8(X0, X1, AH, AM, AL)                                              \
    CVT1(X0[0], 0, AH, AM, AL) CVT1(X0[1], 1, AH, AM, AL)                     \
    CVT1(X0[2], 2, AH, AM, AL) CVT1(X0[3], 3, AH, AM, AL)                     \
    CVT1(X1[0], 4, AH, AM, AL) CVT1(X1[1], 5, AH, AM, AL)                     \
    CVT1(X1[2], 6, AH, AM, AL) CVT1(X1[3], 7, AH, AM, AL)

#define MFMA(A, B, C) __builtin_amdgcn_mfma_f32_16x16x32_bf16(A, B, C, 0, 0, 0)

// one split-product over a 2-cf group: 4 independent acc chains
#define PROD(AREG0, AREG1, BI) {                                              \
    acc[0][cfb]     = MFMA(AREG0, b0[BI], acc[0][cfb]);                       \
    acc[0][cfb + 1] = MFMA(AREG0, b1[BI], acc[0][cfb + 1]);                   \
    acc[1][cfb]     = MFMA(AREG1, b0[BI], acc[1][cfb]);                       \
    acc[1][cfb + 1] = MFMA(AREG1, b1[BI], acc[1][cfb + 1]); }

__global__ __launch_bounds__(64, 4) void gemm_mfma(const float* __restrict__ x,
                                                   const unsigned short* __restrict__ WF,
                                                   float* __restrict__ part,
                                                   int S)
{
    const int l = threadIdx.x;             // 0..63
    const int g = blockIdx.x & 255;        // row group (32 rows)
    const int s = blockIdx.x >> 8;         // k-split
    const int rowbase = g * 32;
    const int kbeg = s * (DMODEL / S);
    const int nsteps = (DMODEL / S) >> 5;  // 32-k steps per wave

    const int lr = l & 15;                 // row (A) / col (B,C) within frag
    const int lk = l >> 4;                 // k-chunk 0..3

    const float* xr0 = x + (size_t)(rowbase + lr) * DMODEL + kbeg + lk * 8;
    const float* xr1 = xr0 + (size_t)16 * DMODEL;
    const unsigned short* wf0 = WF + (size_t)(kbeg >> 5) * 2048 + l * 8;

    f32x4 acc[2][4] = {};
    f32x4 xa[2], xb[2];

    // prologue: A loads for kstep 0
    xa[0] = *(const f32x4*)xr0;  xa[1] = *(const f32x4*)(xr0 + 4);
    xb[0] = *(const f32x4*)xr1;  xb[1] = *(const f32x4*)(xr1 + 4);

    for (int it = 0; it < nsteps; ++it) {
        // convert current A (consumes xa/xb -> frees them for prefetch)
        short8 ah0, am0, al0, ah1, am1, al1;
        CVT8(xa[0], xa[1], ah0, am0, al0)
        CVT8(xb[0], xb[1], ah1, am1, al1)

        // prefetch next kstep's A into the same registers (WAR after CVT)
        if (it + 1 < nsteps) {
            const float* pa = xr0 + (size_t)(it + 1) * 32;
            const float* pb = xr1 + (size_t)(it + 1) * 32;
            xa[0] = *(const f32x4*)pa;  xa[1] = *(const f32x4*)(pa + 4);
            xb[0] = *(const f32x4*)pb;  xb[1] = *(const f32x4*)(pb + 4);
        }

        const unsigned short* wp = wf0 + (size_t)it * 2048;

        // ---- two 2-cf groups; B rolled (24 VGPR live)
#pragma unroll
        for (int grp = 0; grp < 2; ++grp) {
            const int cfb = grp * 2;
            short8 b0[3], b1[3];   // planes h,m,l for cf=cfb and cf=cfb+1
#pragma unroll
            for (int p = 0; p < 3; ++p) {
                b0[p] = *(const short8*)(wp + (size_t)p * WF_PLANE + cfb * 512);
                b1[p] = *(const short8*)(wp + (size_t)p * WF_PLANE + cfb * 512 + 512);
            }
            // 6 products, product-major: 4 independent acc chains each
            PROD(ah0, ah1, 0)   // hH
            PROD(ah0, ah1, 1)   // hM
            PROD(am0, am1, 0)   // mH
            PROD(ah0, ah1, 2)   // hL
            PROD(al0, al1, 0)   // lH
            PROD(am0, am1, 1)   // mM
        }
    }

    // C write: col = lr, row = (l>>4)*4 + reg  (m89-verified layout)
    const int orow = lk * 4;
#pragma unroll
    for (int rf = 0; rf < 2; ++rf)
#pragma unroll
        for (int j = 0; j < 4; ++j) {
            const int row = rowbase + rf * 16 + orow + j;
            float* dst = part + ((size_t)s * BATCH + row) * NEXP + lr;
#pragma unroll
            for (int cf = 0; cf < 4; ++cf)
                dst[cf * 16] = acc[rf][cf][j];
        }
}

// ============================================================================
// Router: sum S partials -> logits; top-2 + softmax weights; softmax accumulation
// ============================================================================
__global__ __launch_bounds__(256) void router2(const float* __restrict__ part,
                                               const float* __restrict__ noise,
                                               float* __restrict__ out,
                                               float* __restrict__ probsum,
                                               float* __restrict__ counts,
                                               int S)
{
    __shared__ float sps[4][64];
    __shared__ float scnt[4][64];

    const int t = threadIdx.x;
    const int w = t >> 6;
    const int lane = t & 63;
    const int wg = blockIdx.x * 4 + w;   // 0..1023

    float* out_idx = out;                 // [8192][2] as float
    float* out_w = out + 16384;           // [8192][2]
    float* out_logits = out + 32768;      // [8192][64]

    float psum_local = 0.f;
    float cnt_local = 0.f;

    for (int r = 0; r < 8; ++r) {
        const int row = wg * 8 + r;
        float lgt = 0.f;
        for (int s = 0; s < S; ++s)
            lgt += part[((size_t)s * BATCH + row) * NEXP + lane];
        out_logits[(size_t)row * NEXP + lane] = lgt;

        const float ny = lgt + 0.1f * noise[(size_t)row * NEXP + lane];

        // top-1 (value, index), tie -> lower index
        float v1 = ny; int i1 = lane;
#pragma unroll
        for (int m = 32; m >= 1; m >>= 1) {
            float ov = __shfl_xor(v1, m);
            int oi = __shfl_xor(i1, m);
            if (ov > v1 || (ov == v1 && oi < i1)) { v1 = ov; i1 = oi; }
        }
        // top-2: mask out winner
        float v2 = (lane == i1) ? -1e30f : ny; int i2 = lane;
#pragma unroll
        for (int m = 32; m >= 1; m >>= 1) {
            float ov = __shfl_xor(v2, m);
            int oi = __shfl_xor(i2, m);
            if (ov > v2 || (ov == v2 && oi < i2)) { v2 = ov; i2 = oi; }
        }

        if (lane == 0) {
            const float d = expf(v2 - v1);      // v1 >= v2
            const float w1 = 1.0f / (1.0f + d);
            out_idx[row * 2 + 0] = (float)i1;
            out_idx[row * 2 + 1] = (float)i2;
            out_w[row * 2 + 0] = w1;
            out_w[row * 2 + 1] = 1.0f - w1;
        }

        // full softmax over clean logits
        float m = lgt;
#pragma unroll
        for (int ss = 32; ss >= 1; ss >>= 1) m = fmaxf(m, __shfl_xor(m, ss));
        const float p = expf(lgt - m);
        float sum = p;
#pragma unroll
        for (int ss = 32; ss >= 1; ss >>= 1) sum += __shfl_xor(sum, ss);
        psum_local += p / sum;
        cnt_local += (lane == i1 ? 1.f : 0.f) + (lane == i2 ? 1.f : 0.f);
    }

    sps[w][lane] = psum_local;
    scnt[w][lane] = cnt_local;
    __syncthreads();
    if (t < 64) {
        float ssum = 0.f, c = 0.f;
#pragma unroll
        for (int ww = 0; ww < 4; ++ww) { ssum += sps[ww][t]; c += scnt[ww][t]; }
        atomicAdd(&probsum[t], ssum);
        atomicAdd(&counts[t], c);
    }
}

// ============================================================================
// Loss
// ============================================================================
__global__ void loss_kernel(const float* __restrict__ probsum,
                            const float* __restrict__ counts,
                            float* __restrict__ out_loss)
{
    const int e = threadIdx.x;
    float v = probsum[e] * counts[e];
#pragma unroll
    for (int s = 32; s >= 1; s >>= 1) v += __shfl_xor(v, s);
    if (e == 0)
        out_loss[0] = (float)NEXP * v / ((float)BATCH * (float)BATCH);
}

// ============================================================================
extern "C" void kernel_launch(void* const* d_in, const int* in_sizes, int n_in,
                              void* d_out, int out_size, void* d_ws, size_t ws_size,
                              hipStream_t stream)
{
    const float* x = (const float*)d_in[0];
    const float* W = (const float*)d_in[1];
    const float* noise = (const float*)d_in[2];
    float* out = (float*)d_out;
    float* ws = (float*)d_ws;

    float* probsum = ws;                                   // 64 floats
    float* counts = ws + 64;                               // 64 floats
    unsigned short* WF = (unsigned short*)(ws + 256);      // 1.5 MB = 393216 floats
    float* part = ws + 256 + WF_FLOATS;                    // S * 8192 * 64 floats

    // pick largest split-K factor that fits the workspace (ws ~536 MB -> S=16)
    int S = 1;
    const size_t base_floats = 256 + WF_FLOATS;
    for (int cand = 16; cand >= 1; cand >>= 1) {
        const size_t need = (base_floats + (size_t)cand * BATCH * NEXP) * sizeof(float);
        if (ws_size >= need) { S = cand; break; }
    }

    hipMemsetAsync(d_ws, 0, 512, stream);

    build_wf<<<128, 256, 0, stream>>>(W, WF);
    gemm_mfma<<<256 * S, 64, 0, stream>>>(x, WF, part, S);
    router2<<<256, 256, 0, stream>>>(part, noise, out, probsum, counts, S);
    loss_kernel<<<1, 64, 0, stream>>>(probsum, counts, out + 557056);
}

// Round 8
// 78.139 us; speedup vs baseline: 1.2843x; 1.2843x over previous
//
#include <hip/hip_runtime.h>
#include <hip/hip_bf16.h>

#define BATCH 8192
#define DMODEL 4096
#define NEXP 64

typedef __attribute__((ext_vector_type(8))) short short8;   // 8 bf16 (4 VGPR)
typedef __attribute__((ext_vector_type(4))) float f32x4;

#define WF_USHORTS 786432   // 128 ksteps * 6144 ushorts (3 planes * 4 cf * 64 lanes * 8)
#define WF_FLOATS  393216

// direct global->LDS async copy, 16B per lane; LDS dest = wave-uniform base + lane*16
#define GLD16(dst_lds, src_g)                                                  \
    __builtin_amdgcn_global_load_lds(                                          \
        (const __attribute__((address_space(1))) void*)(src_g),                \
        (__attribute__((address_space(3))) void*)(dst_lds), 16, 0, 0)

// ============================================================================
// Build W planes (h/m/l bf16 split), per-kstep contiguous:
// WF2[ks][plane][cf][lane][j] <- split of W[e=cf*16+(l&15)][k=ks*32+(l>>4)*8+j]
// ============================================================================
__global__ __launch_bounds__(256) void build_wf(const float* __restrict__ W,
                                                unsigned short* __restrict__ WF2)
{
    const int gid = blockIdx.x * 256 + threadIdx.x;   // 0..32767
    const int ks = gid >> 8;
    const int cf = (gid >> 6) & 3;
    const int l  = gid & 63;
    const int e  = cf * 16 + (l & 15);
    const int k0 = ks * 32 + (l >> 4) * 8;
    const float* src = W + (size_t)e * DMODEL + k0;

    const size_t base = (size_t)ks * 6144 + cf * 512 + l * 8;
#pragma unroll
    for (int j = 0; j < 8; ++j) {
        const float xv = src[j];
        const __hip_bfloat16 h = __float2bfloat16(xv);
        const float r1 = xv - __bfloat162float(h);
        const __hip_bfloat16 m = __float2bfloat16(r1);
        const float r2 = r1 - __bfloat162float(m);
        const __hip_bfloat16 lo = __float2bfloat16(r2);
        WF2[base + j]        = __builtin_bit_cast(unsigned short, h);
        WF2[base + 2048 + j] = __builtin_bit_cast(unsigned short, m);
        WF2[base + 4096 + j] = __builtin_bit_cast(unsigned short, lo);
    }
}

// ============================================================================
// MFMA GEMM, m97-style: 256 threads (4 waves), tile 128 rows x 64 experts,
// BK=32, global_load_lds staging (A swizzled via pre-swizzled global source),
// double-buffered LDS, 1 barrier/kstep. 6-product bf16 split.
// Grid = 64 row-groups x S k-splits. part[s][row][e].
// ============================================================================

#define CVT1(V, J, AH, AM, AL) {                                              \
    const float xv_ = (V);                                                    \
    const __hip_bfloat16 h_ = __float2bfloat16(xv_);                          \
    const float r1_ = xv_ - __bfloat162float(h_);                             \
    const __hip_bfloat16 m_ = __float2bfloat16(r1_);                          \
    const float r2_ = r1_ - __bfloat162float(m_);                             \
    const __hip_bfloat16 l_ = __float2bfloat16(r2_);                          \
    AH[J] = (short)__builtin_bit_cast(unsigned short, h_);                    \
    AM[J] = (short)__builtin_bit_cast(unsigned short, m_);                    \
    AL[J] = (short)__builtin_bit_cast(unsigned short, l_); }

#define CVT8(X0, X1, AH, AM, AL)                                              \
    CVT1(X0[0], 0, AH, AM, AL) CVT1(X0[1], 1, AH, AM, AL)                     \
    CVT1(X0[2], 2, AH, AM, AL) CVT1(X0[3], 3, AH, AM, AL)                     \
    CVT1(X1[0], 4, AH, AM, AL) CVT1(X1[1], 5, AH, AM, AL)                     \
    CVT1(X1[2], 6, AH, AM, AL) CVT1(X1[3], 7, AH, AM, AL)

#define MFMA(A, B, C) __builtin_amdgcn_mfma_f32_16x16x32_bf16(A, B, C, 0, 0, 0)

__global__ __launch_bounds__(256, 2) void gemm_mfma(const float* __restrict__ x,
                                                    const unsigned short* __restrict__ WF2,
                                                    float* __restrict__ part,
                                                    int S)
{
    __shared__ float xs[2][4096];            // A tiles: [buf][128 rows * 32 k], 16 KB each
    __shared__ unsigned short wsh[2][6144];  // B tiles: [buf][3 planes][4 cf][64][8], 12 KB each

    const int t = threadIdx.x;
    const int l = t & 63;
    const int wid = t >> 6;
    const int g = blockIdx.x & 63;           // row group (128 rows)
    const int s = blockIdx.x >> 6;           // k-split
    const int rowbase = g * 128;
    const int kbeg = s * (DMODEL / S);
    const int nsteps = (DMODEL / S) >> 5;    // 32-k steps

    // ---- A staging source pointers (pre-swizzled global source, linear LDS dest)
    // round r: tr = r*32 + wid*8 + (l>>3); stored unit = l&7; logical unit = (l&7)^(tr&7)
    const float* pxa[4];
#pragma unroll
    for (int r = 0; r < 4; ++r) {
        const int tr = r * 32 + wid * 8 + (l >> 3);
        const int ul = (l & 7) ^ (tr & 7);
        pxa[r] = x + (size_t)(rowbase + tr) * DMODEL + kbeg + ul * 4;
    }
    // B staging source (linear copy, round r == plane r)
    const unsigned short* pwb = WF2 + (size_t)(kbeg >> 5) * 6144 + t * 8;

#define STAGE(BUF, IT) {                                                       \
    _Pragma("unroll")                                                          \
    for (int r_ = 0; r_ < 4; ++r_)                                             \
        GLD16(&xs[BUF][r_ * 1024 + wid * 256], pxa[r_] + (size_t)(IT) * 32);   \
    _Pragma("unroll")                                                          \
    for (int r_ = 0; r_ < 3; ++r_)                                             \
        GLD16(&wsh[BUF][r_ * 2048 + wid * 512],                                \
              pwb + (size_t)(IT) * 6144 + r_ * 2048); }

    // ---- compute-side A addresses (apply the same XOR on read)
    const int lr = l & 15;                   // row within frag / col of C
    const int lk = l >> 4;                   // k-chunk 0..3
    const int xr = lr & 7;                   // row XOR key (same for rf=0/1)
    const int tr0 = wid * 32 + lr;
    const int tr1 = tr0 + 16;
    const int a00 = tr0 * 32 + (((lk * 2)     ^ xr) * 4);
    const int a01 = tr0 * 32 + (((lk * 2 + 1) ^ xr) * 4);
    const int a10 = tr1 * 32 + (((lk * 2)     ^ xr) * 4);
    const int a11 = tr1 * 32 + (((lk * 2 + 1) ^ xr) * 4);

    f32x4 acc[2][4] = {};

    STAGE(0, 0)
    __syncthreads();

    for (int it = 0; it < nsteps; ++it) {
        const int cur = it & 1;
        if (it + 1 < nsteps) STAGE(cur ^ 1, it + 1)

        const f32x4 xa0 = *(const f32x4*)&xs[cur][a00];
        const f32x4 xa1 = *(const f32x4*)&xs[cur][a01];
        const f32x4 xb0 = *(const f32x4*)&xs[cur][a10];
        const f32x4 xb1 = *(const f32x4*)&xs[cur][a11];
        short8 ah0, am0, al0, ah1, am1, al1;
        CVT8(xa0, xa1, ah0, am0, al0)
        CVT8(xb0, xb1, ah1, am1, al1)

#pragma unroll
        for (int cf = 0; cf < 4; ++cf) {
            const unsigned short* wp = &wsh[cur][cf * 512 + l * 8];
            const short8 bh = *(const short8*)(wp);
            const short8 bm = *(const short8*)(wp + 2048);
            const short8 bl = *(const short8*)(wp + 4096);
            acc[0][cf] = MFMA(ah0, bh, acc[0][cf]);
            acc[1][cf] = MFMA(ah1, bh, acc[1][cf]);
            acc[0][cf] = MFMA(ah0, bm, acc[0][cf]);
            acc[1][cf] = MFMA(ah1, bm, acc[1][cf]);
            acc[0][cf] = MFMA(am0, bh, acc[0][cf]);
            acc[1][cf] = MFMA(am1, bh, acc[1][cf]);
            acc[0][cf] = MFMA(ah0, bl, acc[0][cf]);
            acc[1][cf] = MFMA(ah1, bl, acc[1][cf]);
            acc[0][cf] = MFMA(al0, bh, acc[0][cf]);
            acc[1][cf] = MFMA(al1, bh, acc[1][cf]);
            acc[0][cf] = MFMA(am0, bm, acc[0][cf]);
            acc[1][cf] = MFMA(am1, bm, acc[1][cf]);
        }
        __syncthreads();
    }

    // ---- C write: col = lr, row = lk*4 + reg (m89-verified layout)
    const int orow = lk * 4;
#pragma unroll
    for (int rf = 0; rf < 2; ++rf)
#pragma unroll
        for (int j = 0; j < 4; ++j) {
            const int row = rowbase + wid * 32 + rf * 16 + orow + j;
            float* dst = part + ((size_t)s * BATCH + row) * NEXP + lr;
#pragma unroll
            for (int cf = 0; cf < 4; ++cf)
                dst[cf * 16] = acc[rf][cf][j];
        }
#undef STAGE
}

// ============================================================================
// Router: sum S partials -> logits; top-2 + softmax weights; softmax accumulation
// ============================================================================
__global__ __launch_bounds__(256) void router2(const float* __restrict__ part,
                                               const float* __restrict__ noise,
                                               float* __restrict__ out,
                                               float* __restrict__ probsum,
                                               float* __restrict__ counts,
                                               int S)
{
    __shared__ float sps[4][64];
    __shared__ float scnt[4][64];

    const int t = threadIdx.x;
    const int w = t >> 6;
    const int lane = t & 63;
    const int wg = blockIdx.x * 4 + w;   // 0..1023

    float* out_idx = out;                 // [8192][2] as float
    float* out_w = out + 16384;           // [8192][2]
    float* out_logits = out + 32768;      // [8192][64]

    float psum_local = 0.f;
    float cnt_local = 0.f;

    for (int r = 0; r < 8; ++r) {
        const int row = wg * 8 + r;
        float lgt = 0.f;
        for (int s = 0; s < S; ++s)
            lgt += part[((size_t)s * BATCH + row) * NEXP + lane];
        out_logits[(size_t)row * NEXP + lane] = lgt;

        const float ny = lgt + 0.1f * noise[(size_t)row * NEXP + lane];

        // top-1 (value, index), tie -> lower index
        float v1 = ny; int i1 = lane;
#pragma unroll
        for (int m = 32; m >= 1; m >>= 1) {
            float ov = __shfl_xor(v1, m);
            int oi = __shfl_xor(i1, m);
            if (ov > v1 || (ov == v1 && oi < i1)) { v1 = ov; i1 = oi; }
        }
        // top-2: mask out winner
        float v2 = (lane == i1) ? -1e30f : ny; int i2 = lane;
#pragma unroll
        for (int m = 32; m >= 1; m >>= 1) {
            float ov = __shfl_xor(v2, m);
            int oi = __shfl_xor(i2, m);
            if (ov > v2 || (ov == v2 && oi < i2)) { v2 = ov; i2 = oi; }
        }

        if (lane == 0) {
            const float d = expf(v2 - v1);      // v1 >= v2
            const float w1 = 1.0f / (1.0f + d);
            out_idx[row * 2 + 0] = (float)i1;
            out_idx[row * 2 + 1] = (float)i2;
            out_w[row * 2 + 0] = w1;
            out_w[row * 2 + 1] = 1.0f - w1;
        }

        // full softmax over clean logits
        float m = lgt;
#pragma unroll
        for (int ss = 32; ss >= 1; ss >>= 1) m = fmaxf(m, __shfl_xor(m, ss));
        const float p = expf(lgt - m);
        float sum = p;
#pragma unroll
        for (int ss = 32; ss >= 1; ss >>= 1) sum += __shfl_xor(sum, ss);
        psum_local += p / sum;
        cnt_local += (lane == i1 ? 1.f : 0.f) + (lane == i2 ? 1.f : 0.f);
    }

    sps[w][lane] = psum_local;
    scnt[w][lane] = cnt_local;
    __syncthreads();
    if (t < 64) {
        float ssum = 0.f, c = 0.f;
#pragma unroll
        for (int ww = 0; ww < 4; ++ww) { ssum += sps[ww][t]; c += scnt[ww][t]; }
        atomicAdd(&probsum[t], ssum);
        atomicAdd(&counts[t], c);
    }
}

// ============================================================================
// Loss
// ============================================================================
__global__ void loss_kernel(const float* __restrict__ probsum,
                            const float* __restrict__ counts,
                            float* __restrict__ out_loss)
{
    const int e = threadIdx.x;
    float v = probsum[e] * counts[e];
#pragma unroll
    for (int s = 32; s >= 1; s >>= 1) v += __shfl_xor(v, s);
    if (e == 0)
        out_loss[0] = (float)NEXP * v / ((float)BATCH * (float)BATCH);
}

// ============================================================================
extern "C" void kernel_launch(void* const* d_in, const int* in_sizes, int n_in,
                              void* d_out, int out_size, void* d_ws, size_t ws_size,
                              hipStream_t stream)
{
    const float* x = (const float*)d_in[0];
    const float* W = (const float*)d_in[1];
    const float* noise = (const float*)d_in[2];
    float* out = (float*)d_out;
    float* ws = (float*)d_ws;

    float* probsum = ws;                                   // 64 floats
    float* counts = ws + 64;                               // 64 floats
    unsigned short* WF2 = (unsigned short*)(ws + 256);     // 1.5 MB
    float* part = ws + 256 + WF_FLOATS;                    // S * 8192 * 64 floats

    int S = 1;
    const size_t base_floats = 256 + WF_FLOATS;
    for (int cand = 8; cand >= 1; cand >>= 1) {
        const size_t need = (base_floats + (size_t)cand * BATCH * NEXP) * sizeof(float);
        if (ws_size >= need) { S = cand; break; }
    }

    hipMemsetAsync(d_ws, 0, 512, stream);

    build_wf<<<128, 256, 0, stream>>>(W, WF2);
    gemm_mfma<<<64 * S, 256, 0, stream>>>(x, WF2, part, S);
    router2<<<256, 256, 0, stream>>>(part, noise, out, probsum, counts, S);
    loss_kernel<<<1, 64, 0, stream>>>(probsum, counts, out + 557056);
}

// Round 9
// 64.443 us; speedup vs baseline: 1.5573x; 1.2125x over previous
//
#include <hip/hip_runtime.h>
#include <hip/hip_bf16.h>

#define BATCH 8192
#define DMODEL 4096
#define NEXP 64

typedef __attribute__((ext_vector_type(8))) short short8;   // 8 bf16 (4 VGPR)
typedef __attribute__((ext_vector_type(4))) float f32x4;

#define WF_USHORTS 786432   // 128 ksteps * 6144 ushorts (3 planes * 4 cf * 64 lanes * 8)
#define WF_FLOATS  393216

// direct global->LDS async copy, 16B per lane; LDS dest = wave-uniform base + lane*16
#define GLD16(dst_lds, src_g)                                                  \
    __builtin_amdgcn_global_load_lds(                                          \
        (const __attribute__((address_space(1))) void*)(src_g),                \
        (__attribute__((address_space(3))) void*)(dst_lds), 16, 0, 0)

// ============================================================================
// Build W planes (h/m/l bf16 split), per-kstep contiguous:
// WF2[ks][plane][cf][lane][j] <- split of W[e=cf*16+(l&15)][k=ks*32+(l>>4)*8+j]
// ============================================================================
__global__ __launch_bounds__(256) void build_wf(const float* __restrict__ W,
                                                unsigned short* __restrict__ WF2)
{
    const int gid = blockIdx.x * 256 + threadIdx.x;   // 0..32767
    const int ks = gid >> 8;
    const int cf = (gid >> 6) & 3;
    const int l  = gid & 63;
    const int e  = cf * 16 + (l & 15);
    const int k0 = ks * 32 + (l >> 4) * 8;
    const float* src = W + (size_t)e * DMODEL + k0;

    const size_t base = (size_t)ks * 6144 + cf * 512 + l * 8;
#pragma unroll
    for (int j = 0; j < 8; ++j) {
        const float xv = src[j];
        const __hip_bfloat16 h = __float2bfloat16(xv);
        const float r1 = xv - __bfloat162float(h);
        const __hip_bfloat16 m = __float2bfloat16(r1);
        const float r2 = r1 - __bfloat162float(m);
        const __hip_bfloat16 lo = __float2bfloat16(r2);
        WF2[base + j]        = __builtin_bit_cast(unsigned short, h);
        WF2[base + 2048 + j] = __builtin_bit_cast(unsigned short, m);
        WF2[base + 4096 + j] = __builtin_bit_cast(unsigned short, lo);
    }
}

// ============================================================================
// MFMA GEMM: 256 threads (4 waves), tile 128 rows x 64 experts, BK=32,
// global_load_lds staging, double-buffered LDS, counted-vmcnt 2-barrier phase
// (never vmcnt(0) in main loop). Each wave stages the 32 A-rows it consumes.
// 6-product bf16 h/m/l split == fp32-accurate logits.
// Grid = 64 row-groups x S k-splits. part[s][row][e].
// ============================================================================

#define CVT1(V, J, AH, AM, AL) {                                              \
    const float xv_ = (V);                                                    \
    const __hip_bfloat16 h_ = __float2bfloat16(xv_);                          \
    const float r1_ = xv_ - __bfloat162float(h_);                             \
    const __hip_bfloat16 m_ = __float2bfloat16(r1_);                          \
    const float r2_ = r1_ - __bfloat162float(m_);                             \
    const __hip_bfloat16 l_ = __float2bfloat16(r2_);                          \
    AH[J] = (short)__builtin_bit_cast(unsigned short, h_);                    \
    AM[J] = (short)__builtin_bit_cast(unsigned short, m_);                    \
    AL[J] = (short)__builtin_bit_cast(unsigned short, l_); }

#define CVT8(X0, X1, AH, AM, AL)                                              \
    CVT1(X0[0], 0, AH, AM, AL) CVT1(X0[1], 1, AH, AM, AL)                     \
    CVT1(X0[2], 2, AH, AM, AL) CVT1(X0[3], 3, AH, AM, AL)                     \
    CVT1(X1[0], 4, AH, AM, AL) CVT1(X1[1], 5, AH, AM, AL)                     \
    CVT1(X1[2], 6, AH, AM, AL) CVT1(X1[3], 7, AH, AM, AL)

#define MFMA(A, B, C) __builtin_amdgcn_mfma_f32_16x16x32_bf16(A, B, C, 0, 0, 0)

__global__ __launch_bounds__(256, 2) void gemm_mfma(const float* __restrict__ x,
                                                    const unsigned short* __restrict__ WF2,
                                                    float* __restrict__ part,
                                                    int S)
{
    __shared__ float xs[2][4096];            // A tiles: [buf][128 rows * 32 k], 16 KB each
    __shared__ unsigned short wsh[2][6144];  // B tiles: [buf][3 planes][4 cf][64][8], 12 KB each

    const int t = threadIdx.x;
    const int l = t & 63;
    const int wid = t >> 6;
    const int g = blockIdx.x & 63;           // row group (128 rows)
    const int s = blockIdx.x >> 6;           // k-split
    const int rowbase = g * 128;
    const int kbeg = s * (DMODEL / S);
    const int nsteps = (DMODEL / S) >> 5;    // 32-k steps

    // ---- A staging: wave wid stages rows wid*32 .. wid*32+31 (its OWN rows).
    // round r: tr = wid*32 + r*8 + (l>>3); stored unit = l&7; logical = (l&7)^(tr&7)
    const float* pxa[4];
#pragma unroll
    for (int r = 0; r < 4; ++r) {
        const int tr = wid * 32 + r * 8 + (l >> 3);
        const int ul = (l & 7) ^ (tr & 7);               // tr&7 == l>>3
        pxa[r] = x + (size_t)(rowbase + tr) * DMODEL + kbeg + ul * 4;
    }
    // B staging source (linear cooperative copy)
    const unsigned short* pwb = WF2 + (size_t)(kbeg >> 5) * 6144 + t * 8;

#define STAGE(BUF, IT) {                                                       \
    _Pragma("unroll")                                                          \
    for (int r_ = 0; r_ < 4; ++r_)                                             \
        GLD16(&xs[BUF][wid * 1024 + r_ * 256], pxa[r_] + (size_t)(IT) * 32);   \
    _Pragma("unroll")                                                          \
    for (int r_ = 0; r_ < 3; ++r_)                                             \
        GLD16(&wsh[BUF][r_ * 2048 + wid * 512],                                \
              pwb + (size_t)(IT) * 6144 + r_ * 2048); }

    // ---- compute-side A addresses (apply the same XOR on read)
    const int lr = l & 15;                   // row within frag / col of C
    const int lk = l >> 4;                   // k-chunk 0..3
    const int xr = lr & 7;                   // row XOR key (same for rf=0/1)
    const int tr0 = wid * 32 + lr;
    const int tr1 = tr0 + 16;
    const int a00 = tr0 * 32 + (((lk * 2)     ^ xr) * 4);
    const int a01 = tr0 * 32 + (((lk * 2 + 1) ^ xr) * 4);
    const int a10 = tr1 * 32 + (((lk * 2)     ^ xr) * 4);
    const int a11 = tr1 * 32 + (((lk * 2 + 1) ^ xr) * 4);

    f32x4 acc[2][4] = {};

    STAGE(0, 0)

    for (int it = 0; it < nsteps; ++it) {
        const int cur = it & 1;
        if (it + 1 < nsteps) {
            STAGE(cur ^ 1, it + 1)
            // wait own current-tile loads (7 newer next-tile loads stay in flight)
            asm volatile("s_waitcnt vmcnt(7)" ::: "memory");
        } else {
            asm volatile("s_waitcnt vmcnt(0)" ::: "memory");
        }
        // all waves waited their own current-tile loads => whole tile landed
        __builtin_amdgcn_s_barrier();

        const f32x4 xa0 = *(const f32x4*)&xs[cur][a00];
        const f32x4 xa1 = *(const f32x4*)&xs[cur][a01];
        const f32x4 xb0 = *(const f32x4*)&xs[cur][a10];
        const f32x4 xb1 = *(const f32x4*)&xs[cur][a11];
        short8 ah0, am0, al0, ah1, am1, al1;
        CVT8(xa0, xa1, ah0, am0, al0)
        CVT8(xb0, xb1, ah1, am1, al1)

#pragma unroll
        for (int cf = 0; cf < 4; ++cf) {
            const unsigned short* wp = &wsh[cur][cf * 512 + l * 8];
            const short8 bh = *(const short8*)(wp);
            const short8 bm = *(const short8*)(wp + 2048);
            const short8 bl = *(const short8*)(wp + 4096);
            acc[0][cf] = MFMA(ah0, bh, acc[0][cf]);
            acc[1][cf] = MFMA(ah1, bh, acc[1][cf]);
            acc[0][cf] = MFMA(ah0, bm, acc[0][cf]);
            acc[1][cf] = MFMA(ah1, bm, acc[1][cf]);
            acc[0][cf] = MFMA(am0, bh, acc[0][cf]);
            acc[1][cf] = MFMA(am1, bh, acc[1][cf]);
            acc[0][cf] = MFMA(ah0, bl, acc[0][cf]);
            acc[1][cf] = MFMA(ah1, bl, acc[1][cf]);
            acc[0][cf] = MFMA(al0, bh, acc[0][cf]);
            acc[1][cf] = MFMA(al1, bh, acc[1][cf]);
            acc[0][cf] = MFMA(am0, bm, acc[0][cf]);
            acc[1][cf] = MFMA(am1, bm, acc[1][cf]);
        }
        // all waves done reading buffer cur -> safe to overwrite next iteration
        __builtin_amdgcn_s_barrier();
    }

    // ---- C write: col = lr, row = lk*4 + reg (m89-verified layout)
    const int orow = lk * 4;
#pragma unroll
    for (int rf = 0; rf < 2; ++rf)
#pragma unroll
        for (int j = 0; j < 4; ++j) {
            const int row = rowbase + wid * 32 + rf * 16 + orow + j;
            float* dst = part + ((size_t)s * BATCH + row) * NEXP + lr;
#pragma unroll
            for (int cf = 0; cf < 4; ++cf)
                dst[cf * 16] = acc[rf][cf][j];
        }
#undef STAGE
}

// ============================================================================
// Router: sum S partials -> logits; top-2 + softmax weights; softmax accumulation
// ============================================================================
template<int NS>
__global__ __launch_bounds__(256) void router2(const float* __restrict__ part,
                                               const float* __restrict__ noise,
                                               float* __restrict__ out,
                                               float* __restrict__ probsum,
                                               float* __restrict__ counts)
{
    __shared__ float sps[4][64];
    __shared__ float scnt[4][64];

    const int t = threadIdx.x;
    const int w = t >> 6;
    const int lane = t & 63;
    const int wg = blockIdx.x * 4 + w;   // 0..1023

    float* out_idx = out;                 // [8192][2] as float
    float* out_w = out + 16384;           // [8192][2]
    float* out_logits = out + 32768;      // [8192][64]

    float psum_local = 0.f;
    float cnt_local = 0.f;

    for (int r = 0; r < 8; ++r) {
        const int row = wg * 8 + r;
        float lgt = 0.f;
#pragma unroll
        for (int s = 0; s < NS; ++s)
            lgt += part[((size_t)s * BATCH + row) * NEXP + lane];
        out_logits[(size_t)row * NEXP + lane] = lgt;

        const float ny = lgt + 0.1f * noise[(size_t)row * NEXP + lane];

        // top-1 (value, index), tie -> lower index
        float v1 = ny; int i1 = lane;
#pragma unroll
        for (int m = 32; m >= 1; m >>= 1) {
            float ov = __shfl_xor(v1, m);
            int oi = __shfl_xor(i1, m);
            if (ov > v1 || (ov == v1 && oi < i1)) { v1 = ov; i1 = oi; }
        }
        // top-2: mask out winner
        float v2 = (lane == i1) ? -1e30f : ny; int i2 = lane;
#pragma unroll
        for (int m = 32; m >= 1; m >>= 1) {
            float ov = __shfl_xor(v2, m);
            int oi = __shfl_xor(i2, m);
            if (ov > v2 || (ov == v2 && oi < i2)) { v2 = ov; i2 = oi; }
        }

        if (lane == 0) {
            const float d = expf(v2 - v1);      // v1 >= v2
            const float w1 = 1.0f / (1.0f + d);
            out_idx[row * 2 + 0] = (float)i1;
            out_idx[row * 2 + 1] = (float)i2;
            out_w[row * 2 + 0] = w1;
            out_w[row * 2 + 1] = 1.0f - w1;
        }

        // full softmax over clean logits
        float m = lgt;
#pragma unroll
        for (int ss = 32; ss >= 1; ss >>= 1) m = fmaxf(m, __shfl_xor(m, ss));
        const float p = expf(lgt - m);
        float sum = p;
#pragma unroll
        for (int ss = 32; ss >= 1; ss >>= 1) sum += __shfl_xor(sum, ss);
        psum_local += p / sum;
        cnt_local += (lane == i1 ? 1.f : 0.f) + (lane == i2 ? 1.f : 0.f);
    }

    sps[w][lane] = psum_local;
    scnt[w][lane] = cnt_local;
    __syncthreads();
    if (t < 64) {
        float ssum = 0.f, c = 0.f;
#pragma unroll
        for (int ww = 0; ww < 4; ++ww) { ssum += sps[ww][t]; c += scnt[ww][t]; }
        atomicAdd(&probsum[t], ssum);
        atomicAdd(&counts[t], c);
    }
}

// ============================================================================
// Loss
// ============================================================================
__global__ void loss_kernel(const float* __restrict__ probsum,
                            const float* __restrict__ counts,
                            float* __restrict__ out_loss)
{
    const int e = threadIdx.x;
    float v = probsum[e] * counts[e];
#pragma unroll
    for (int s = 32; s >= 1; s >>= 1) v += __shfl_xor(v, s);
    if (e == 0)
        out_loss[0] = (float)NEXP * v / ((float)BATCH * (float)BATCH);
}

// ============================================================================
extern "C" void kernel_launch(void* const* d_in, const int* in_sizes, int n_in,
                              void* d_out, int out_size, void* d_ws, size_t ws_size,
                              hipStream_t stream)
{
    const float* x = (const float*)d_in[0];
    const float* W = (const float*)d_in[1];
    const float* noise = (const float*)d_in[2];
    float* out = (float*)d_out;
    float* ws = (float*)d_ws;

    float* probsum = ws;                                   // 64 floats
    float* counts = ws + 64;                               // 64 floats
    unsigned short* WF2 = (unsigned short*)(ws + 256);     // 1.5 MB
    float* part = ws + 256 + WF_FLOATS;                    // S * 8192 * 64 floats

    int S = 1;
    const size_t base_floats = 256 + WF_FLOATS;
    for (int cand = 8; cand >= 1; cand >>= 1) {
        const size_t need = (base_floats + (size_t)cand * BATCH * NEXP) * sizeof(float);
        if (ws_size >= need) { S = cand; break; }
    }

    hipMemsetAsync(d_ws, 0, 512, stream);

    build_wf<<<128, 256, 0, stream>>>(W, WF2);
    gemm_mfma<<<64 * S, 256, 0, stream>>>(x, WF2, part, S);
    switch (S) {
        case 8: router2<8><<<256, 256, 0, stream>>>(part, noise, out, probsum, counts); break;
        case 4: router2<4><<<256, 256, 0, stream>>>(part, noise, out, probsum, counts); break;
        case 2: router2<2><<<256, 256, 0, stream>>>(part, noise, out, probsum, counts); break;
        default: router2<1><<<256, 256, 0, stream>>>(part, noise, out, probsum, counts); break;
    }
    loss_kernel<<<1, 64, 0, stream>>>(probsum, counts, out + 557056);
}